// Round 7
// baseline (3692.516 us; speedup 1.0000x reference)
//
#include <hip/hip_runtime.h>

// GAWADecoder on MI355X (gfx950). All tensors fp32 in global; bf16 MFMA inside.
// R8 post-mortem (unified theory of R3-R8): every variant streams 1.15MB of
// weights per block per step at a latency-limited ~25GB/s/CU (VGPR_Count=64 in
// ALL rounds -> ~1-2 outstanding 1KB loads/wave at ~400cyc L2 latency ->
// 47us/step regardless of traffic, occupancy, or layout). R9: TRADE TLP FOR
// ILP. 256-thread blocks (4 waves), __launch_bounds__(256,1) -> 512-VGPR
// budget; each wave owns 64 cols (4 col-groups) so the allocator can keep
// 8-12 weight loads in flight. Gate biases folded into packed tables; gi0
// inputs repacked [row][col][gates] (8B vector gathers); __expf-based gates.

typedef __bf16 bf16;
typedef __attribute__((ext_vector_type(8))) __bf16 bf16x8;
typedef __attribute__((ext_vector_type(4))) __bf16 bf16x4;
typedef __attribute__((ext_vector_type(4))) float fx4;

#define MFMA16(a, b, c) __builtin_amdgcn_mfma_f32_16x16x32_bf16(a, b, c, 0, 0, 0)

__device__ __forceinline__ float fastrcp(float x) { return __builtin_amdgcn_rcpf(x); }
__device__ __forceinline__ float sigm_f(float x) { return fastrcp(1.0f + __expf(-x)); }
__device__ __forceinline__ float tanh_f(float x) { return 1.0f - 2.0f * fastrcp(__expf(2.0f * x) + 1.0f); }

// load 8 consecutive fp32, round to bf16x8 (MFMA operand)
__device__ __forceinline__ bf16x8 cvt8(const float* __restrict__ p) {
    float4 u = ((const float4*)p)[0];
    float4 v = ((const float4*)p)[1];
    bf16x8 r;
    r[0] = (bf16)u.x; r[1] = (bf16)u.y; r[2] = (bf16)u.z; r[3] = (bf16)u.w;
    r[4] = (bf16)v.x; r[5] = (bf16)v.y; r[6] = (bf16)v.z; r[7] = (bf16)v.w;
    return r;
}

// bf16x8 h + fp32[8] -> bf16x8 (logits A-fragment: h1 + attn_out)
__device__ __forceinline__ bf16x8 addcvt8(bf16x8 h, const float* __restrict__ p) {
    float4 u = ((const float4*)p)[0];
    float4 v = ((const float4*)p)[1];
    bf16x8 r;
    r[0] = (bf16)((float)h[0] + u.x); r[1] = (bf16)((float)h[1] + u.y);
    r[2] = (bf16)((float)h[2] + u.z); r[3] = (bf16)((float)h[3] + u.w);
    r[4] = (bf16)((float)h[4] + v.x); r[5] = (bf16)((float)h[5] + v.y);
    r[6] = (bf16)((float)h[6] + v.z); r[7] = (bf16)((float)h[7] + v.w);
    return r;
}

// ---------------------------------------------------------------------------
__global__ void f2b(const float* __restrict__ s, bf16* __restrict__ d, int n) {
    int i = (blockIdx.x * 256 + threadIdx.x) * 4;
    if (i >= n) return;
    float4 v = *(const float4*)(s + i);
    bf16x4 o;
    o[0] = (bf16)v.x; o[1] = (bf16)v.y; o[2] = (bf16)v.z; o[3] = (bf16)v.w;
    *(bf16x4*)(d + i) = o;
}

// ---------------------------------------------------------------------------
// Repack a (768,256) fp32 weight matrix into per-col-group linear bf16 slabs:
//   slab s (16 cols s*16..s*16+16), elem ((c*3+g)*512 + l16*32 + quad*8)
// Every wave-wide load in the loop reads a contiguous 1KB from one slab.
// ---------------------------------------------------------------------------
__global__ void wpack(const float* __restrict__ src, bf16* __restrict__ dst) {
    int gid = blockIdx.x * 256 + threadIdx.x;     // 768*32 pieces of 8 elems
    if (gid >= 768 * 32) return;
    int gc = gid >> 5, piece = gid & 31;
    int g = gc >> 8, rem = gc & 255, w = rem >> 4, l16 = rem & 15;
    int c = piece >> 2, quad = piece & 3;
    bf16x8 v = cvt8(src + (size_t)gc * 256 + piece * 8);
    size_t d = (size_t)w * 12288 + (size_t)(c * 3 + g) * 512 + l16 * 32 + quad * 8;
    *(bf16x8*)(dst + d) = v;
}

// ---------------------------------------------------------------------------
// gpack: gwb2[row][col][4] = { gword_r + b_hh0_r, gword_z + b_hh0_z, gword_n, 0 }
// (gword already includes b_ih0 from the GEMM). 8B vector per (row,col).
// ---------------------------------------------------------------------------
__global__ void gpack(const float* __restrict__ g, const float* __restrict__ bhh0,
                      bf16* __restrict__ o) {
    int i = blockIdx.x * 256 + threadIdx.x;
    if (i >= 4096 * 256) return;
    int row = i >> 8, col = i & 255;
    const float* s = g + (size_t)row * 768 + col;
    bf16x4 v;
    v[0] = (bf16)(s[0]   + bhh0[col]);
    v[1] = (bf16)(s[256] + bhh0[256 + col]);
    v[2] = (bf16)(s[512]);
    v[3] = (bf16)0.0f;
    *(bf16x4*)(o + (size_t)i * 4) = v;
}

// cpack: cpb2[id][col][4] = { cproj_r, cproj_z, cproj_n, 0 }
__global__ void cpack(const float* __restrict__ c, bf16* __restrict__ o) {
    int i = blockIdx.x * 256 + threadIdx.x;
    if (i >= 256 * 256) return;
    int row = i >> 8, col = i & 255;
    const float* s = c + (size_t)row * 768 + col;
    bf16x4 v;
    v[0] = (bf16)s[0]; v[1] = (bf16)s[256]; v[2] = (bf16)s[512]; v[3] = (bf16)0.0f;
    *(bf16x4*)(o + (size_t)i * 4) = v;
}

// bprep: biasT[col] = (bi1_r+bh1_r, bi1_z+bh1_z, bi1_n, bh1_n); bh0n[col]
__global__ void bprep(const float* __restrict__ bi1, const float* __restrict__ bh1,
                      const float* __restrict__ bhh0,
                      float4* __restrict__ biasT, float* __restrict__ bh0n) {
    int c = threadIdx.x;
    biasT[c] = make_float4(bi1[c] + bh1[c], bi1[256 + c] + bh1[256 + c],
                           bi1[512 + c], bh1[512 + c]);
    bh0n[c] = bhh0[512 + c];
}

// ---------------------------------------------------------------------------
// out[M,N] = act(A[M,K] @ W[N,K]^T + bias), fp32 in global; bf16 MFMA inside.
// ---------------------------------------------------------------------------
__global__ __launch_bounds__(256, 4) void gemm_bt(
    const float* __restrict__ A, int lda,
    const float* __restrict__ W, int ldw,
    const float* __restrict__ bias,
    float* __restrict__ out, int ldo, int act_tanh, int K)
{
    const int tid  = threadIdx.x;
    const int wid  = tid >> 6;
    const int lane = tid & 63;
    const int quad = lane >> 4;
    const int l16  = lane & 15;
    const int m0   = blockIdx.x * 32;
    const int n0   = blockIdx.y * 256 + wid * 64;

    fx4 acc[4][2];
#pragma unroll
    for (int j = 0; j < 4; ++j) {
        acc[j][0] = fx4{0.f, 0.f, 0.f, 0.f};
        acc[j][1] = fx4{0.f, 0.f, 0.f, 0.f};
    }

    const float* a0p = A + (size_t)(m0 + l16) * lda + quad * 8;
    const float* a1p = A + (size_t)(m0 + 16 + l16) * lda + quad * 8;

    for (int k0 = 0; k0 < K; k0 += 32) {
        bf16x8 a0 = cvt8(a0p + k0);
        bf16x8 a1 = cvt8(a1p + k0);
#pragma unroll
        for (int j = 0; j < 4; ++j) {
            bf16x8 b = cvt8(W + (size_t)(n0 + j * 16 + l16) * ldw + k0 + quad * 8);
            acc[j][0] = MFMA16(a0, b, acc[j][0]);
            acc[j][1] = MFMA16(a1, b, acc[j][1]);
        }
    }

#pragma unroll
    for (int j = 0; j < 4; ++j) {
        int n = n0 + j * 16 + l16;
        float bv = bias ? bias[n] : 0.0f;
#pragma unroll
        for (int rt = 0; rt < 2; ++rt)
#pragma unroll
            for (int r = 0; r < 4; ++r) {
                int m = m0 + rt * 16 + quad * 4 + r;
                float v = acc[j][rt][r] + bv;
                if (act_tanh) v = tanhf(v);
                out[(size_t)m * ldo + n] = v;
            }
    }
}

// ---------------------------------------------------------------------------
// Persistent recurrent kernel. 256 blocks x 256 thr (4 waves, 1/SIMD), 16 rows
// per block, wave w owns cols [w*64, w*64+64) = 4 col-groups of 16.
// __launch_bounds__(256,1) -> 512-VGPR budget so weight loads pipeline deep.
// Two barriers/step, block-local LDS ping-pong:
//   phase A: gh0 = h0(t-1)@w_hh0^T (12 MFMA-chains; 12 weight loads/kk)
//            -> layer-0 gates -> h0(t). barrier.
//   phase B: gi1 = h0(t)@w_ih1^T then gh1 = h1(t-1)@w_hh1^T (24 chains)
//            -> layer-1 gates -> h1(t) (+NT archive). barrier.
// ---------------------------------------------------------------------------
__global__ __launch_bounds__(256, 1) void decoder_loop(
    const int*   __restrict__ tgt,      // (4096,32)
    const float* __restrict__ h0i,      // (4096,256)
    const bf16*  __restrict__ gwb2,     // (4096,256,4) gi0 word part (+biases)
    const bf16*  __restrict__ cpb2,     // (256,256,4)  gi0 char part
    const bf16*  __restrict__ w_hh0p,   // packed slabs
    const bf16*  __restrict__ w_ih1p,
    const bf16*  __restrict__ w_hh1p,
    const float4* __restrict__ biasT,   // (256) L1 bias table
    const float* __restrict__ bh0nT,    // (256) b_hh0 n-gate
    bf16* __restrict__ h1all)           // (4096,32,256) bf16
{
    __shared__ __align__(16) bf16 hb0[2][16][264];
    __shared__ __align__(16) bf16 hb1[2][16][264];

    const int tid  = threadIdx.x;
    const int w    = tid >> 6;     // 0..3
    const int lane = tid & 63;
    const int quad = lane >> 4;
    const int l16  = lane & 15;
    const int row0 = blockIdx.x * 16;
    const int rw   = quad * 4;

    // per-wave slab bases (cg adds cg*12288 at compile time in unrolled loops)
    const int lofs = l16 * 32 + quad * 8;
    const bf16* pW0 = w_hh0p + (size_t)(4 * w) * 12288 + lofs;
    const bf16* pW1 = w_ih1p + (size_t)(4 * w) * 12288 + lofs;
    const bf16* pW2 = w_hh1p + (size_t)(4 * w) * 12288 + lofs;

    // per-cg bias constants
    float4 bT[4]; float b0n[4];
#pragma unroll
    for (int cg = 0; cg < 4; ++cg) {
        int colw = w * 64 + cg * 16 + l16;
        bT[cg]  = biasT[colw];
        b0n[cg] = bh0nT[colw];
    }

    // init h state in LDS
#pragma unroll
    for (int cg = 0; cg < 4; ++cg)
#pragma unroll
        for (int r = 0; r < 4; ++r) {
            int colw = w * 64 + cg * 16 + l16;
            float v = h0i[(size_t)(row0 + rw + r) * 256 + colw];
            bf16 b = (bf16)v;
            hb0[0][rw + r][colw] = b;
            hb1[0][rw + r][colw] = b;
        }
    __syncthreads();

    for (int t = 0; t < 32; ++t) {
        const int p = t & 1, q = p ^ 1;

        // ---- gi0 gather: cg inputs as 8B vectors (issued before phase A) ----
        int ids[4];
#pragma unroll
        for (int r = 0; r < 4; ++r)
            ids[r] = (t == 0) ? 1 : tgt[(row0 + rw + r) * 32 + (t - 1)];
        float cgr[4][4], cgz[4][4], cgn[4][4];
#pragma unroll
        for (int cg = 0; cg < 4; ++cg)
#pragma unroll
            for (int r = 0; r < 4; ++r) {
                int colw = w * 64 + cg * 16 + l16;
                bf16x4 gv = *(const bf16x4*)(gwb2 + ((size_t)(row0 + rw + r) * 256 + colw) * 4);
                bf16x4 cv = *(const bf16x4*)(cpb2 + ((size_t)ids[r] * 256 + colw) * 4);
                cgr[cg][r] = (float)gv[0] + (float)cv[0];
                cgz[cg][r] = (float)gv[1] + (float)cv[1];
                cgn[cg][r] = (float)gv[2] + (float)cv[2];
            }

        // -------- phase A: gh0 = h0(t-1) @ w_hh0^T --------
        fx4 g0[4][3];
#pragma unroll
        for (int cg = 0; cg < 4; ++cg)
#pragma unroll
            for (int g = 0; g < 3; ++g) g0[cg][g] = fx4{0.f, 0.f, 0.f, 0.f};
#pragma unroll
        for (int kk = 0; kk < 8; ++kk) {
            bf16x8 a = *(const bf16x8*)&hb0[p][l16][kk * 32 + quad * 8];
#pragma unroll
            for (int cg = 0; cg < 4; ++cg)
#pragma unroll
                for (int g = 0; g < 3; ++g) {
                    bf16x8 wv = *(const bf16x8*)(pW0 + cg * 12288 + (kk * 3 + g) * 512);
                    g0[cg][g] = MFMA16(a, wv, g0[cg][g]);
                }
        }
        // layer-0 gates -> h0(t)
#pragma unroll
        for (int cg = 0; cg < 4; ++cg) {
            int colw = w * 64 + cg * 16 + l16;
#pragma unroll
            for (int r = 0; r < 4; ++r) {
                float hold = (float)hb0[p][rw + r][colw];
                float rr = sigm_f(cgr[cg][r] + g0[cg][0][r]);
                float zz = sigm_f(cgz[cg][r] + g0[cg][1][r]);
                float nn = tanh_f(cgn[cg][r] + rr * (g0[cg][2][r] + b0n[cg]));
                hb0[q][rw + r][colw] = (bf16)((1.0f - zz) * nn + zz * hold);
            }
        }
        __syncthreads();   // B1: h0(t) visible

        // -------- phase B: gi1 = h0(t)@w_ih1^T ; gh1 = h1(t-1)@w_hh1^T -------
        fx4 gi[4][3], gh[4][3];
#pragma unroll
        for (int cg = 0; cg < 4; ++cg)
#pragma unroll
            for (int g = 0; g < 3; ++g) {
                gi[cg][g] = fx4{0.f, 0.f, 0.f, 0.f};
                gh[cg][g] = fx4{0.f, 0.f, 0.f, 0.f};
            }
#pragma unroll
        for (int kk = 0; kk < 8; ++kk) {
            bf16x8 a = *(const bf16x8*)&hb0[q][l16][kk * 32 + quad * 8];
#pragma unroll
            for (int cg = 0; cg < 4; ++cg)
#pragma unroll
                for (int g = 0; g < 3; ++g) {
                    bf16x8 wv = *(const bf16x8*)(pW1 + cg * 12288 + (kk * 3 + g) * 512);
                    gi[cg][g] = MFMA16(a, wv, gi[cg][g]);
                }
        }
#pragma unroll
        for (int kk = 0; kk < 8; ++kk) {
            bf16x8 c = *(const bf16x8*)&hb1[p][l16][kk * 32 + quad * 8];
#pragma unroll
            for (int cg = 0; cg < 4; ++cg)
#pragma unroll
                for (int g = 0; g < 3; ++g) {
                    bf16x8 wv = *(const bf16x8*)(pW2 + cg * 12288 + (kk * 3 + g) * 512);
                    gh[cg][g] = MFMA16(c, wv, gh[cg][g]);
                }
        }
        // layer-1 gates -> h1(t)
#pragma unroll
        for (int cg = 0; cg < 4; ++cg) {
            int colw = w * 64 + cg * 16 + l16;
#pragma unroll
            for (int r = 0; r < 4; ++r) {
                float hold = (float)hb1[p][rw + r][colw];
                float rr = sigm_f(gi[cg][0][r] + gh[cg][0][r] + bT[cg].x);
                float zz = sigm_f(gi[cg][1][r] + gh[cg][1][r] + bT[cg].y);
                float nn = tanh_f(gi[cg][2][r] + bT[cg].z + rr * (gh[cg][2][r] + bT[cg].w));
                bf16 hv = (bf16)((1.0f - zz) * nn + zz * hold);
                hb1[q][rw + r][colw] = hv;
                __builtin_nontemporal_store(
                    hv, &h1all[((size_t)(row0 + rw + r) * 32 + t) * 256 + colw]);
            }
        }
        __syncthreads();   // B2: h1(t) visible
    }
}

// ---------------------------------------------------------------------------
// Final logits: out[m,v] = (h1[m,:] + a2[m>>5,:]) @ pw^T + pb[v],  M=131072.
// ---------------------------------------------------------------------------
__global__ __launch_bounds__(256, 4) void logits_final(
    const bf16*  __restrict__ h1,    // (131072,256) bf16
    const float* __restrict__ a2,    // (4096,256) attn_out (fp32)
    const bf16*  __restrict__ pw,    // (256,256) bf16
    const float* __restrict__ pb,    // (256,)
    float* __restrict__ out)         // (131072,256)
{
    const int tid  = threadIdx.x;
    const int wid  = tid >> 6;
    const int lane = tid & 63;
    const int quad = lane >> 4;
    const int l16  = lane & 15;
    const int m0   = blockIdx.x * 32;
    const int n0   = wid * 64;
    const int b    = m0 >> 5;          // all 32 rows share one batch index

    fx4 acc[4][2];
#pragma unroll
    for (int j = 0; j < 4; ++j) {
        acc[j][0] = fx4{0.f, 0.f, 0.f, 0.f};
        acc[j][1] = fx4{0.f, 0.f, 0.f, 0.f};
    }

    for (int k0 = 0; k0 < 256; k0 += 32) {
        bf16x8 h0 = *(const bf16x8*)(h1 + (size_t)(m0 + l16) * 256 + k0 + quad * 8);
        bf16x8 h1v = *(const bf16x8*)(h1 + (size_t)(m0 + 16 + l16) * 256 + k0 + quad * 8);
        const float* ap = a2 + (size_t)b * 256 + k0 + quad * 8;
        bf16x8 a0 = addcvt8(h0, ap);
        bf16x8 a1 = addcvt8(h1v, ap);
#pragma unroll
        for (int j = 0; j < 4; ++j) {
            bf16x8 bb = *(const bf16x8*)(pw + (size_t)(n0 + j * 16 + l16) * 256 + k0 + quad * 8);
            acc[j][0] = MFMA16(a0, bb, acc[j][0]);
            acc[j][1] = MFMA16(a1, bb, acc[j][1]);
        }
    }

#pragma unroll
    for (int j = 0; j < 4; ++j) {
        int n = n0 + j * 16 + l16;
        float bv = pb[n];
#pragma unroll
        for (int rt = 0; rt < 2; ++rt)
#pragma unroll
            for (int r = 0; r < 4; ++r) {
                int m = m0 + rt * 16 + quad * 4 + r;
                out[(size_t)m * 256 + n] = acc[j][rt][r] + bv;
            }
    }
}

// ---------------------------------------------------------------------------
extern "C" void kernel_launch(void* const* d_in, const int* in_sizes, int n_in,
                              void* d_out, int out_size, void* d_ws, size_t ws_size,
                              hipStream_t stream)
{
    const float* eword      = (const float*)d_in[0];
    const int*   tgt        = (const int*)  d_in[1];
    const float* char_emb   = (const float*)d_in[2];
    const float* ew_w       = (const float*)d_in[3];
    const float* ew_b       = (const float*)d_in[4];
    const float* w_ih0      = (const float*)d_in[5];   // (768, 832)
    const float* w_hh0      = (const float*)d_in[6];
    const float* b_ih0      = (const float*)d_in[7];
    const float* b_hh0      = (const float*)d_in[8];
    const float* w_ih1      = (const float*)d_in[9];
    const float* w_hh1      = (const float*)d_in[10];
    const float* b_ih1      = (const float*)d_in[11];
    const float* b_hh1      = (const float*)d_in[12];
    const float* attn_in_w  = (const float*)d_in[13];  // wq|wk|wv (q,k dead)
    const float* attn_in_b  = (const float*)d_in[14];
    const float* attn_out_w = (const float*)d_in[15];
    const float* attn_out_b = (const float*)d_in[16];
    // d_in[17..18] key_w/key_b dead (len-1 softmax)
    const float* val_w      = (const float*)d_in[19];
    const float* val_b      = (const float*)d_in[20];
    const float* proj_w     = (const float*)d_in[21];
    const float* proj_b     = (const float*)d_in[22];

    char* ws = (char*)d_ws;
    float* h0i   = (float*)ws;  ws += (size_t)4096 * 256 * 4;   //  4 MB
    float* gwrd  = (float*)ws;  ws += (size_t)4096 * 768 * 4;   // 12 MB
    float* cproj = (float*)ws;  ws += (size_t)256  * 768 * 4;   // .75 MB
    float* a2    = (float*)ws;  ws += (size_t)4096 * 256 * 4;   //  4 MB
    // 8 MB region: prologue uses it as fp32 buf1/buf2 (attn chain); then gpack
    // overwrites it with gwb2 (8 MB bf16) — stream-ordered, no overlap.
    char*  hreg  = ws;          ws += (size_t)8 * 1024 * 1024;
    float* buf1  = (float*)hreg;                          // 4 MB (t1)
    float* buf2  = (float*)(hreg + (size_t)4*1024*1024);  // 4 MB (ev)
    bf16*  gwb2  = (bf16*)hreg;                           // (4096,256,4) bf16
    bf16*  cpb2  = (bf16*)ws;   ws += (size_t)256 * 256 * 4 * 2;  // .5 MB
    bf16*  wbhh0 = (bf16*)ws;   ws += (size_t)768 * 256 * 2;      // packed slabs
    bf16*  wbih1 = (bf16*)ws;   ws += (size_t)768 * 256 * 2;
    bf16*  wbhh1 = (bf16*)ws;   ws += (size_t)768 * 256 * 2;
    bf16*  wbprj = (bf16*)ws;   ws += (size_t)256 * 256 * 2;
    float4* biasT = (float4*)ws; ws += 256 * 16;
    float* bh0nT = (float*)ws;  ws += 256 * 4;
    bf16*  h1all = (bf16*)ws;   ws += (size_t)4096 * 32 * 256 * 2;  // 67 MB

    dim3 blk(256);
    // pack loop weights into per-col-group linear slabs (bf16)
    wpack<<<dim3(96), blk, 0, stream>>>(w_hh0, wbhh0);
    wpack<<<dim3(96), blk, 0, stream>>>(w_ih1, wbih1);
    wpack<<<dim3(96), blk, 0, stream>>>(w_hh1, wbhh1);
    f2b<<<dim3(64),  blk, 0, stream>>>(proj_w, wbprj, 256 * 256);
    bprep<<<dim3(1), blk, 0, stream>>>(b_ih1, b_hh1, b_hh0, biasT, bh0nT);

    // h0 = tanh(eword @ ew_w^T + ew_b)
    gemm_bt<<<dim3(128, 1), blk, 0, stream>>>(eword, 768, ew_w, 768, ew_b, h0i, 256, 1, 768);
    // gword = eword @ w_ih0[:,64:]^T + b_ih0
    gemm_bt<<<dim3(128, 3), blk, 0, stream>>>(eword, 768, w_ih0 + 64, 832, b_ih0, gwrd, 768, 0, 768);
    // cproj = char_emb @ w_ih0[:,:64]^T   (PAD row of char_emb is zero)
    gemm_bt<<<dim3(8, 3),   blk, 0, stream>>>(char_emb, 64, w_ih0, 832, nullptr, cproj, 768, 0, 64);
    // attention chain (static): t1 = ew@vw^T+vb; ev = t1@wv^T+bv; a2 = ev@ao^T+ab
    gemm_bt<<<dim3(128, 1), blk, 0, stream>>>(eword, 768, val_w, 768, val_b, buf1, 256, 0, 768);
    gemm_bt<<<dim3(128, 1), blk, 0, stream>>>(buf1, 256, attn_in_w + 512 * 256, 256, attn_in_b + 512, buf2, 256, 0, 256);
    gemm_bt<<<dim3(128, 1), blk, 0, stream>>>(buf2, 256, attn_out_w, 256, attn_out_b, a2, 256, 0, 256);

    // pack gi0 inputs as [row][col][gates] 8B vectors (after buf1/buf2 retire)
    gpack<<<dim3(4096), blk, 0, stream>>>(gwrd, b_hh0, gwb2);
    cpack<<<dim3(256),  blk, 0, stream>>>(cproj, cpb2);

    // recurrent decode: 256 blocks x 256 thr (4 waves, deep per-wave ILP)
    decoder_loop<<<dim3(256), blk, 0, stream>>>(
        tgt, h0i, gwb2, cpb2, wbhh0, wbih1, wbhh1, biasT, bh0nT, h1all);

    // batched logits: out = (h1 + a2) @ pw^T + pb
    logits_final<<<dim3(4096), blk, 0, stream>>>(h1all, a2, wbprj, proj_b, (float*)d_out);
}